// Round 6
// baseline (273.995 us; speedup 1.0000x reference)
//
#include <hip/hip_runtime.h>

typedef unsigned int u32;
typedef unsigned long long u64;
typedef __bf16 bf16x8 __attribute__((ext_vector_type(8)));
typedef float f32x4 __attribute__((ext_vector_type(4)));

// Problem constants
#define N_PIX   32768        // 8*64*64 pixels
#define C_DIM   64
#define NE      8192
#define HW      4096         // 64*64
#define BHW     262144       // elements per batch in z (64*4096)
#define ZQ_N    2097152      // 8*64*64*64

// Output layout (flat f32): [0]=loss, [1..2097152]=z_q_out(NCHW), [2097153..]=idx
#define OUT_ZQ_OFF  1
#define OUT_IDX_OFF (1 + ZQ_N)

// Scratch inside d_out's zq region (overwritten by k_final at the end).
// SCR = out + 4 floats (16B aligned). Offsets in 4-byte slots relative to SCR:
#define OFF_ZH   0         // u32[1048576]  : zh bf16 pairs, [pixel][feat]
#define OFF_EH   1048576   // u32[262144]   : eh bf16 pairs, [code][feat]
#define OFF_S    1310720   // f32[32768]    : ||z||^2 exact pairwise
#define OFF_W    1343488   // f32[32768]    : refine window per pixel
#define OFF_CMIN 1376256   // u32[32768]    : order-encoded coarse min
#define OFF_LIST 1409024   // u32[CAP]      : candidate (pixel<<13|code)
#define CAP      655360

// Workspace (ws) layout:
#define WS_E_OFF  262144   // f32 Etab[8192] after u64 best[32768]
#define WS_C_OFF  294912   // u32 count
#define WS_L_OFF  294976   // f64 lpart[128]

// GEMM tiling: block = 256 thr = 4 waves = 2 row-groups x 2 code-groups.
// Each wave: 64 pixel-rows (A in registers), 512 codes streamed from L2.
#define M_BLK   128
#define N_SLICE 1024
#define LOCBUF  1024       // per-block candidate staging (expected ~24/block)

__device__ __forceinline__ u32 encf(float v) {
    u32 u = __float_as_uint(v);
    return (u & 0x80000000u) ? ~u : (u | 0x80000000u);
}
__device__ __forceinline__ float decf(u32 k) {
    return (k & 0x80000000u) ? __uint_as_float(k ^ 0x80000000u)
                             : __uint_as_float(~k);
}
__device__ __forceinline__ u32 bf16rn(float v) {      // RNE f32->bf16 bits
    u32 u = __float_as_uint(v);
    return (u + 0x7FFFu + ((u >> 16) & 1u)) >> 16;
}
__device__ __forceinline__ int swz(int row, int kg) { // 16B-chunk LDS swizzle
    return row * 8 + (kg ^ (row & 7));
}

__global__ __launch_bounds__(256) void k_init(u64* __restrict__ best,
                                              u32* __restrict__ cmin,
                                              u32* __restrict__ count,
                                              double* __restrict__ lpart) {
    int i = blockIdx.x * 256 + threadIdx.x;
    if (i < N_PIX) { best[i] = ~0ull; cmin[i] = 0xFFFFFFFFu; }
    if (i < 128)   lpart[i] = 0.0;
    if (i == 0)    *count = 0u;
}

// z: compute exact-pairwise S, Sum|z| -> window, and bf16 z in [pixel][feat].
__global__ __launch_bounds__(256) void k_prep_z(const float* __restrict__ z,
                                                u32* __restrict__ zh,
                                                float* __restrict__ Sarr,
                                                float* __restrict__ Wp) {
    __shared__ u32 lw[256 * 33];
    const int tid = threadIdx.x;
    const int p   = blockIdx.x * 256 + tid;
    const float* zp = z + (p >> 12) * BHW + (p & 4095);
    float r[8]; float asum = 0.0f; u32 prev = 0;
#pragma unroll
    for (int c = 0; c < C_DIM; ++c) {
        float v  = zp[c * HW];                    // coalesced
        float sq = __fmul_rn(v, v);
        if (c < 8) r[c] = sq; else r[c & 7] = __fadd_rn(r[c & 7], sq);
        asum += fabsf(v);
        u32 hb = bf16rn(v);
        if (c & 1) lw[tid * 33 + (c >> 1)] = prev | (hb << 16);
        else       prev = hb;
    }
    Sarr[p] = __fadd_rn(__fadd_rn(__fadd_rn(r[0], r[1]), __fadd_rn(r[2], r[3])),
                        __fadd_rn(__fadd_rn(r[4], r[5]), __fadd_rn(r[6], r[7])));
    Wp[p]   = 5.0e-5f * asum + 1.0e-4f;   // rigorous bf16 bound + quant slack
    __syncthreads();
#pragma unroll
    for (int j = 0; j < 32; ++j) {        // coalesced u32 writes
        int lg = j * 256 + tid;
        zh[blockIdx.x * 8192 + lg] = lw[(lg >> 5) * 33 + (lg & 31)];
    }
}

// emb: exact-pairwise ||e||^2 table + bf16 codebook [code][feat].
__global__ __launch_bounds__(256) void k_prep_e(const float* __restrict__ emb,
                                                u32* __restrict__ eh,
                                                float* __restrict__ Etab) {
    __shared__ u32 lw[256 * 33];
    const int tid = threadIdx.x;
    const int m   = blockIdx.x * 256 + tid;
    const float* rp = emb + m * C_DIM;
    float r[8]; u32 prev = 0;
#pragma unroll
    for (int c = 0; c < C_DIM; ++c) {
        float v  = rp[c];
        float sq = __fmul_rn(v, v);
        if (c < 8) r[c] = sq; else r[c & 7] = __fadd_rn(r[c & 7], sq);
        u32 hb = bf16rn(v);
        if (c & 1) lw[tid * 33 + (c >> 1)] = prev | (hb << 16);
        else       prev = hb;
    }
    Etab[m] = __fadd_rn(__fadd_rn(__fadd_rn(r[0], r[1]), __fadd_rn(r[2], r[3])),
                        __fadd_rn(__fadd_rn(r[4], r[5]), __fadd_rn(r[6], r[7])));
    __syncthreads();
#pragma unroll
    for (int j = 0; j < 32; ++j) {
        int lg = j * 256 + tid;
        eh[blockIdx.x * 8192 + lg] = lw[(lg >> 5) * 33 + (lg & 31)];
    }
}

// Coarse GEMM, barrier-free K-loop (round-5 postmortem: 2-barrier staged
// version idled 75% at 2 blocks/CU). A tile (128 rows) staged once to LDS,
// each wave holds 64 rows as register fragments; B (codebook) streamed
// per-wave straight from L2 (eh = 2 MB, fits per-XCD L2), no barriers.
// PASS 0: per-pixel coarse min -> global atomicMin(cmin, order-encoded).
// PASS 1: collect (pixel,code) with t <= cmin+W via LDS staging buffer,
//         one global ticket per block (round-4 lesson).
template <int PASS>
__global__ __launch_bounds__(256) void k_gemm(const uint4* __restrict__ zh4,
                                              const bf16x8* __restrict__ eh8,
                                              const float* __restrict__ Etab,
                                              const float* __restrict__ Wp,
                                              u32* __restrict__ cmin,
                                              u32* __restrict__ count,
                                              u32* __restrict__ list) {
    __shared__ uint4 a4[M_BLK * 8];      // 16 KB z tile (swizzled 16B chunks)
    __shared__ float thr_l[M_BLK];       // pass-1 thresholds
    __shared__ u32 loc_list[LOCBUF];     // 4 KB pass-1 candidate staging
    __shared__ u32 loc_cnt, glob_base;

    const int tid  = threadIdx.x;
    const int lane = tid & 63, w = tid >> 6;
    const int rg_id = w & 1;             // row-group: 64 rows each
    const int cg_id = w >> 1;            // code-group: 512 codes each
    const int q = lane >> 4, c15 = lane & 15;
    const int pixbase   = blockIdx.x * M_BLK;
    const int slicebase = blockIdx.y * N_SLICE;

    // Stage A tile (coalesced) into swizzled LDS.
#pragma unroll
    for (int it = 0; it < 4; ++it) {
        int idx = it * 256 + tid;                       // = p*8 + kg
        a4[swz(idx >> 3, idx & 7)] = zh4[blockIdx.x * 1024 + idx];
    }
    if (PASS == 1 && tid < M_BLK)
        thr_l[tid] = decf(cmin[pixbase + tid]) + Wp[pixbase + tid];
    if (PASS == 1 && tid == 0) loc_cnt = 0u;
    __syncthreads();                     // the ONLY pre-flush barrier

    // A fragments: af[rowtile][khalf]; A-operand m-index = c15.
    const bf16x8* a_bf = reinterpret_cast<const bf16x8*>(a4);
    bf16x8 af[4][2];
#pragma unroll
    for (int rt = 0; rt < 4; ++rt)
#pragma unroll
        for (int h = 0; h < 2; ++h)
            af[rt][h] = a_bf[swz(rg_id * 64 + rt * 16 + c15, h * 4 + q)];

    float vmin[16];
    float thr_reg[16];
#pragma unroll
    for (int i = 0; i < 16; ++i) vmin[i] = 3.402823466e38f;
    if (PASS == 1) {
#pragma unroll
        for (int rt = 0; rt < 4; ++rt)
#pragma unroll
            for (int rg = 0; rg < 4; ++rg)
                thr_reg[rt * 4 + rg] = thr_l[rg_id * 64 + rt * 16 + q * 4 + rg];
    }

    // Wave-owned code range: 512 codes, streamed from L2, no barriers.
    const int code0 = slicebase + cg_id * 512;
    const bf16x8* bp  = eh8 + (size_t)(code0 + c15) * 8 + q;
    const float*  evp = Etab + code0 + c15;

#pragma unroll 2
    for (int cg = 0; cg < 32; ++cg) {
        bf16x8 bf0 = bp[0];              // bytes [q*16 .. ) of 16 code rows
        bf16x8 bf1 = bp[4];              // second k-half
        float  Ev  = *evp;
#pragma unroll
        for (int rt = 0; rt < 4; ++rt) {
            f32x4 acc = {0.f, 0.f, 0.f, 0.f};
            acc = __builtin_amdgcn_mfma_f32_16x16x32_bf16(af[rt][0], bf0, acc, 0, 0, 0);
            acc = __builtin_amdgcn_mfma_f32_16x16x32_bf16(af[rt][1], bf1, acc, 0, 0, 0);
#pragma unroll
            for (int rg = 0; rg < 4; ++rg) {
                float t = __builtin_fmaf(acc[rg], -2.0f, Ev);
                if (PASS == 0) {
                    vmin[rt * 4 + rg] = fminf(vmin[rt * 4 + rg], t);
                } else {
                    if (t <= thr_reg[rt * 4 + rg]) {
                        int pixel = pixbase + rg_id * 64 + rt * 16 + q * 4 + rg;
                        int code  = code0 + cg * 16 + c15;
                        u32 entry = ((u32)pixel << 13) | (u32)code;
                        u32 pos = atomicAdd(&loc_cnt, 1u);      // LDS ticket
                        if (pos < LOCBUF) {
                            loc_list[pos] = entry;
                        } else {                                // ~never
                            u32 g = atomicAdd(count, 1u);
                            if (g < CAP) list[g] = entry;
                        }
                    }
                }
            }
        }
        bp += 128; evp += 16;
    }

    if (PASS == 0) {
        // Reduce over the 16 code-columns (c15 lanes), then global combine.
#pragma unroll
        for (int i = 0; i < 16; ++i) {
            float v = vmin[i];
            v = fminf(v, __shfl_xor(v, 1));
            v = fminf(v, __shfl_xor(v, 2));
            v = fminf(v, __shfl_xor(v, 4));
            v = fminf(v, __shfl_xor(v, 8));
            if (c15 == 0) {
                int row = rg_id * 64 + (i >> 2) * 16 + q * 4 + (i & 3);
                atomicMin(&cmin[pixbase + row], encf(v));
            }
        }
    } else {
        // Block-level flush: one global ticket, coalesced list writes.
        __syncthreads();
        u32 n_loc = loc_cnt; if (n_loc > LOCBUF) n_loc = LOCBUF;
        if (tid == 0) glob_base = atomicAdd(count, n_loc);
        __syncthreads();
        u32 base = glob_base;
        for (u32 i = tid; i < n_loc; i += 256u) {
            u32 g = base + i;
            if (g < CAP) list[g] = loc_list[i];
        }
    }
}

// Exact refine: bit-identical reference distance chain per candidate pair.
__global__ __launch_bounds__(256) void k_refine(const float* __restrict__ z,
                                                const float* __restrict__ emb,
                                                const float* __restrict__ Sarr,
                                                const float* __restrict__ Etab,
                                                const u32* __restrict__ count,
                                                const u32* __restrict__ list,
                                                u64* __restrict__ best) {
    u32 cnt = *count; if (cnt > CAP) cnt = CAP;
    for (u32 i = blockIdx.x * 256 + threadIdx.x; i < cnt; i += 256u * 256u) {
        u32 e = list[i];
        int pixel = (int)(e >> 13), code = (int)(e & 8191u);
        const float* zp = z + (pixel >> 12) * BHW + (pixel & 4095);
        const float* ep = emb + code * C_DIM;
        float dot = 0.0f;
#pragma unroll
        for (int c = 0; c < C_DIM; ++c)
            dot = __builtin_fmaf(zp[c * HW], ep[c], dot);
        float dist = __fsub_rn(__fadd_rn(Sarr[pixel], Etab[code]),
                               __fmul_rn(2.0f, dot));
        u64 key = ((u64)__float_as_uint(dist) << 32) | (u32)code;  // dist > 0
        atomicMin(&best[pixel], key);
    }
}

// Gather z_q, write idx + z_q_st (NCHW), accumulate f64 loss partials.
__global__ __launch_bounds__(256) void k_final(const float* __restrict__ z,
                                               const float* __restrict__ emb,
                                               const u64* __restrict__ best,
                                               float* __restrict__ out,
                                               double* __restrict__ lpart) {
    const int n  = blockIdx.x * 256 + threadIdx.x;
    const int b  = n >> 12;
    const int hw = n & 4095;
    const u32 m  = (u32)(best[n] & 0xFFFFFFFFull);
    out[OUT_IDX_OFF + n] = (float)m;

    const float* zp = z + b * BHW + hw;
    const float* e  = emb + m * C_DIM;
    double lacc = 0.0;
#pragma unroll
    for (int c = 0; c < 64; ++c) {
        float zz   = zp[c * HW];
        float ec   = e[c];
        float diff = __fsub_rn(ec, zz);
        float outv = __fadd_rn(zz, diff);
        out[OUT_ZQ_OFF + b * BHW + c * HW + hw] = outv;
        lacc += (double)__fmul_rn(diff, diff);
    }
    __shared__ double sh[256];
    sh[threadIdx.x] = lacc;
    __syncthreads();
#pragma unroll
    for (int s = 128; s > 0; s >>= 1) {
        if (threadIdx.x < s) sh[threadIdx.x] += sh[threadIdx.x + s];
        __syncthreads();
    }
    if (threadIdx.x == 0) lpart[blockIdx.x] = sh[0];
}

__global__ void k_loss(const double* __restrict__ lpart, float* __restrict__ out) {
    if (threadIdx.x == 0 && blockIdx.x == 0) {
        double s = 0.0;
        for (int i = 0; i < 128; ++i) s += lpart[i];
        float m1 = (float)(s / (double)ZQ_N);
        out[0] = __fadd_rn(m1, __fmul_rn(0.25f, m1));
    }
}

extern "C" void kernel_launch(void* const* d_in, const int* in_sizes, int n_in,
                              void* d_out, int out_size, void* d_ws, size_t ws_size,
                              hipStream_t stream) {
    const float* z   = (const float*)d_in[0];
    const float* emb = (const float*)d_in[1];
    float* out = (float*)d_out;

    char* ws = (char*)d_ws;
    u64*    best  = (u64*)ws;
    float*  Etab  = (float*)(ws + WS_E_OFF);
    u32*    count = (u32*)(ws + WS_C_OFF);
    double* lpart = (double*)(ws + WS_L_OFF);

    float* SCR = out + 4;                       // 16B-aligned scratch in zq region
    u32*   zh   = (u32*)(SCR + OFF_ZH);
    u32*   eh   = (u32*)(SCR + OFF_EH);
    float* Sarr = SCR + OFF_S;
    float* Wp   = SCR + OFF_W;
    u32*   cmin = (u32*)(SCR + OFF_CMIN);
    u32*   list = (u32*)(SCR + OFF_LIST);

    k_init  <<<dim3(N_PIX / 256), dim3(256), 0, stream>>>(best, cmin, count, lpart);
    k_prep_z<<<dim3(N_PIX / 256), dim3(256), 0, stream>>>(z, zh, Sarr, Wp);
    k_prep_e<<<dim3(NE / 256),    dim3(256), 0, stream>>>(emb, eh, Etab);
    k_gemm<0><<<dim3(N_PIX / M_BLK, NE / N_SLICE), dim3(256), 0, stream>>>(
        (const uint4*)zh, (const bf16x8*)eh, Etab, Wp, cmin, count, list);
    k_gemm<1><<<dim3(N_PIX / M_BLK, NE / N_SLICE), dim3(256), 0, stream>>>(
        (const uint4*)zh, (const bf16x8*)eh, Etab, Wp, cmin, count, list);
    k_refine<<<dim3(256), dim3(256), 0, stream>>>(z, emb, Sarr, Etab, count, list, best);
    k_final <<<dim3(N_PIX / 256), dim3(256), 0, stream>>>(z, emb, best, out, lpart);
    k_loss  <<<dim3(1), dim3(64), 0, stream>>>(lpart, out);
}

// Round 7
// 253.566 us; speedup vs baseline: 1.0806x; 1.0806x over previous
//
#include <hip/hip_runtime.h>

typedef unsigned int u32;
typedef unsigned long long u64;
typedef __bf16 bf16x8 __attribute__((ext_vector_type(8)));
typedef float f32x4 __attribute__((ext_vector_type(4)));

// Problem constants
#define N_PIX   32768        // 8*64*64 pixels
#define C_DIM   64
#define NE      8192
#define HW      4096         // 64*64
#define BHW     262144       // elements per batch in z (64*4096)
#define ZQ_N    2097152      // 8*64*64*64

// Output layout (flat f32): [0]=loss, [1..2097152]=z_q_out(NCHW), [2097153..]=idx
#define OUT_ZQ_OFF  1
#define OUT_IDX_OFF (1 + ZQ_N)

// Scratch inside d_out's zq region (overwritten by k_final at the end).
// SCR = out + 4 floats (16B aligned). Offsets in 4-byte slots relative to SCR:
#define OFF_ZH   0         // u32[1048576]  : zh bf16 pairs, [pixel][feat]
#define OFF_EH   1048576   // u32[262144]   : eh bf16 pairs, [code][feat]
#define OFF_S    1310720   // f32[32768]    : ||z||^2 exact pairwise
#define OFF_W    1343488   // f32[32768]    : refine window per pixel
#define OFF_CMIN 1376256   // u32[32768]    : order-encoded coarse min
#define OFF_LIST 1409024   // u32[CAP]      : candidate (pixel<<13|code)
#define CAP      655360

// Workspace (ws) layout:
#define WS_E_OFF  262144   // f32 Etab[8192] after u64 best[32768]
#define WS_C_OFF  294912   // u32 count
#define WS_L_OFF  294976   // f64 lpart[128]

// GEMM tiling: block = 256 thr = 4 waves = 2 row-groups x 2 code-groups.
// Each wave: 64 pixel-rows (A in registers), 512 codes streamed from L2.
#define M_BLK   128
#define N_SLICE 1024
#define LOCBUF  1024       // per-block candidate staging (expected ~24/block)

__device__ __forceinline__ u32 encf(float v) {
    u32 u = __float_as_uint(v);
    return (u & 0x80000000u) ? ~u : (u | 0x80000000u);
}
__device__ __forceinline__ float decf(u32 k) {
    return (k & 0x80000000u) ? __uint_as_float(k ^ 0x80000000u)
                             : __uint_as_float(~k);
}
__device__ __forceinline__ u32 bf16rn(float v) {      // RNE f32->bf16 bits
    u32 u = __float_as_uint(v);
    return (u + 0x7FFFu + ((u >> 16) & 1u)) >> 16;
}
__device__ __forceinline__ int swz(int row, int kg) { // 16B-chunk LDS swizzle
    return row * 8 + (kg ^ (row & 7));
}

__global__ __launch_bounds__(256) void k_init(u64* __restrict__ best,
                                              u32* __restrict__ cmin,
                                              u32* __restrict__ count,
                                              double* __restrict__ lpart) {
    int i = blockIdx.x * 256 + threadIdx.x;
    if (i < N_PIX) { best[i] = ~0ull; cmin[i] = 0xFFFFFFFFu; }
    if (i < 128)   lpart[i] = 0.0;
    if (i == 0)    *count = 0u;
}

// z: compute exact-pairwise S, Sum|z| -> window, and bf16 z in [pixel][feat].
__global__ __launch_bounds__(256) void k_prep_z(const float* __restrict__ z,
                                                u32* __restrict__ zh,
                                                float* __restrict__ Sarr,
                                                float* __restrict__ Wp) {
    __shared__ u32 lw[256 * 33];
    const int tid = threadIdx.x;
    const int p   = blockIdx.x * 256 + tid;
    const float* zp = z + (p >> 12) * BHW + (p & 4095);
    float r[8]; float asum = 0.0f; u32 prev = 0;
#pragma unroll
    for (int c = 0; c < C_DIM; ++c) {
        float v  = zp[c * HW];                    // coalesced
        float sq = __fmul_rn(v, v);
        if (c < 8) r[c] = sq; else r[c & 7] = __fadd_rn(r[c & 7], sq);
        asum += fabsf(v);
        u32 hb = bf16rn(v);
        if (c & 1) lw[tid * 33 + (c >> 1)] = prev | (hb << 16);
        else       prev = hb;
    }
    Sarr[p] = __fadd_rn(__fadd_rn(__fadd_rn(r[0], r[1]), __fadd_rn(r[2], r[3])),
                        __fadd_rn(__fadd_rn(r[4], r[5]), __fadd_rn(r[6], r[7])));
    Wp[p]   = 5.0e-5f * asum + 1.0e-4f;   // rigorous bf16 bound + quant slack
    __syncthreads();
#pragma unroll
    for (int j = 0; j < 32; ++j) {        // coalesced u32 writes
        int lg = j * 256 + tid;
        zh[blockIdx.x * 8192 + lg] = lw[(lg >> 5) * 33 + (lg & 31)];
    }
}

// emb: exact-pairwise ||e||^2 table + bf16 codebook [code][feat].
__global__ __launch_bounds__(256) void k_prep_e(const float* __restrict__ emb,
                                                u32* __restrict__ eh,
                                                float* __restrict__ Etab) {
    __shared__ u32 lw[256 * 33];
    const int tid = threadIdx.x;
    const int m   = blockIdx.x * 256 + tid;
    const float* rp = emb + m * C_DIM;
    float r[8]; u32 prev = 0;
#pragma unroll
    for (int c = 0; c < C_DIM; ++c) {
        float v  = rp[c];
        float sq = __fmul_rn(v, v);
        if (c < 8) r[c] = sq; else r[c & 7] = __fadd_rn(r[c & 7], sq);
        u32 hb = bf16rn(v);
        if (c & 1) lw[tid * 33 + (c >> 1)] = prev | (hb << 16);
        else       prev = hb;
    }
    Etab[m] = __fadd_rn(__fadd_rn(__fadd_rn(r[0], r[1]), __fadd_rn(r[2], r[3])),
                        __fadd_rn(__fadd_rn(r[4], r[5]), __fadd_rn(r[6], r[7])));
    __syncthreads();
#pragma unroll
    for (int j = 0; j < 32; ++j) {
        int lg = j * 256 + tid;
        eh[blockIdx.x * 8192 + lg] = lw[(lg >> 5) * 33 + (lg & 31)];
    }
}

// Coarse GEMM, barrier-free K-loop. Round-6 postmortem: compiler allocated
// only 40 VGPRs -> A fragments re-read from LDS every iteration, latency-
// bound at 12% MfmaUtil. Fix: __launch_bounds__(256,4) caps VGPR at 128
// (room for af[4][2]+vmin+thr resident) and explicit register double-buffer
// on the B stream so L2 latency overlaps MFMA+epilogue.
// PASS 0: per-pixel coarse min -> global atomicMin(cmin, order-encoded).
// PASS 1: collect (pixel,code) with t <= cmin+W via LDS staging buffer,
//         one global ticket per block (round-4 lesson).
template <int PASS>
__global__ __launch_bounds__(256, 4) void k_gemm(const uint4* __restrict__ zh4,
                                                 const bf16x8* __restrict__ eh8,
                                                 const float* __restrict__ Etab,
                                                 const float* __restrict__ Wp,
                                                 u32* __restrict__ cmin,
                                                 u32* __restrict__ count,
                                                 u32* __restrict__ list) {
    __shared__ uint4 a4[M_BLK * 8];      // 16 KB z tile (swizzled 16B chunks)
    __shared__ float thr_l[M_BLK];       // pass-1 thresholds
    __shared__ u32 loc_list[LOCBUF];     // 4 KB pass-1 candidate staging
    __shared__ u32 loc_cnt, glob_base;

    const int tid  = threadIdx.x;
    const int lane = tid & 63, w = tid >> 6;
    const int rg_id = w & 1;             // row-group: 64 rows each
    const int cg_id = w >> 1;            // code-group: 512 codes each
    const int q = lane >> 4, c15 = lane & 15;
    const int pixbase   = blockIdx.x * M_BLK;
    const int slicebase = blockIdx.y * N_SLICE;

    // Issue first B prefetch EARLY (before LDS staging) so it overlaps.
    const int code0 = slicebase + cg_id * 512;
    const bf16x8* bp  = eh8 + (size_t)(code0 + c15) * 8 + q;
    const float*  evp = Etab + code0 + c15;
    bf16x8 nb0 = bp[0];
    bf16x8 nb1 = bp[4];
    float  nEv = *evp;

    // Stage A tile (coalesced) into swizzled LDS.
#pragma unroll
    for (int it = 0; it < 4; ++it) {
        int idx = it * 256 + tid;                       // = p*8 + kg
        a4[swz(idx >> 3, idx & 7)] = zh4[blockIdx.x * 1024 + idx];
    }
    if (PASS == 1 && tid < M_BLK)
        thr_l[tid] = decf(cmin[pixbase + tid]) + Wp[pixbase + tid];
    if (PASS == 1 && tid == 0) loc_cnt = 0u;
    __syncthreads();                     // the ONLY pre-flush barrier

    // A fragments: af[rowtile][khalf]; A-operand m-index = c15. Register-
    // resident for the whole K-loop (128-VGPR budget).
    const bf16x8* a_bf = reinterpret_cast<const bf16x8*>(a4);
    bf16x8 af[4][2];
#pragma unroll
    for (int rt = 0; rt < 4; ++rt)
#pragma unroll
        for (int h = 0; h < 2; ++h)
            af[rt][h] = a_bf[swz(rg_id * 64 + rt * 16 + c15, h * 4 + q)];

    float vmin[16];
    float thr_reg[16];
#pragma unroll
    for (int i = 0; i < 16; ++i) vmin[i] = 3.402823466e38f;
    if (PASS == 1) {
#pragma unroll
        for (int rt = 0; rt < 4; ++rt)
#pragma unroll
            for (int rg = 0; rg < 4; ++rg)
                thr_reg[rt * 4 + rg] = thr_l[rg_id * 64 + rt * 16 + q * 4 + rg];
    }

    // Wave-owned code range: 512 codes streamed from L2, no barriers.
    // Register double-buffer: consume (b0,b1,Ev) while (nb0,nb1,nEv) fly.
#pragma unroll 4
    for (int cg = 0; cg < 32; ++cg) {
        bf16x8 b0 = nb0, b1 = nb1;
        float  Ev = nEv;
        if (cg < 31) {
            bp += 128; evp += 16;
            nb0 = bp[0];
            nb1 = bp[4];
            nEv = *evp;
        }
#pragma unroll
        for (int rt = 0; rt < 4; ++rt) {
            f32x4 acc = {0.f, 0.f, 0.f, 0.f};
            acc = __builtin_amdgcn_mfma_f32_16x16x32_bf16(af[rt][0], b0, acc, 0, 0, 0);
            acc = __builtin_amdgcn_mfma_f32_16x16x32_bf16(af[rt][1], b1, acc, 0, 0, 0);
#pragma unroll
            for (int rg = 0; rg < 4; ++rg) {
                float t = __builtin_fmaf(acc[rg], -2.0f, Ev);
                if (PASS == 0) {
                    vmin[rt * 4 + rg] = fminf(vmin[rt * 4 + rg], t);
                } else {
                    if (t <= thr_reg[rt * 4 + rg]) {
                        int pixel = pixbase + rg_id * 64 + rt * 16 + q * 4 + rg;
                        int code  = code0 + cg * 16 + c15;
                        u32 entry = ((u32)pixel << 13) | (u32)code;
                        u32 pos = atomicAdd(&loc_cnt, 1u);      // LDS ticket
                        if (pos < LOCBUF) {
                            loc_list[pos] = entry;
                        } else {                                // ~never
                            u32 g = atomicAdd(count, 1u);
                            if (g < CAP) list[g] = entry;
                        }
                    }
                }
            }
        }
    }

    if (PASS == 0) {
        // Reduce over the 16 code-columns (c15 lanes), then global combine.
#pragma unroll
        for (int i = 0; i < 16; ++i) {
            float v = vmin[i];
            v = fminf(v, __shfl_xor(v, 1));
            v = fminf(v, __shfl_xor(v, 2));
            v = fminf(v, __shfl_xor(v, 4));
            v = fminf(v, __shfl_xor(v, 8));
            if (c15 == 0) {
                int row = rg_id * 64 + (i >> 2) * 16 + q * 4 + (i & 3);
                atomicMin(&cmin[pixbase + row], encf(v));
            }
        }
    } else {
        // Block-level flush: one global ticket, coalesced list writes.
        __syncthreads();
        u32 n_loc = loc_cnt; if (n_loc > LOCBUF) n_loc = LOCBUF;
        if (tid == 0) glob_base = atomicAdd(count, n_loc);
        __syncthreads();
        u32 base = glob_base;
        for (u32 i = tid; i < n_loc; i += 256u) {
            u32 g = base + i;
            if (g < CAP) list[g] = loc_list[i];
        }
    }
}

// Exact refine: bit-identical reference distance chain per candidate pair.
__global__ __launch_bounds__(256) void k_refine(const float* __restrict__ z,
                                                const float* __restrict__ emb,
                                                const float* __restrict__ Sarr,
                                                const float* __restrict__ Etab,
                                                const u32* __restrict__ count,
                                                const u32* __restrict__ list,
                                                u64* __restrict__ best) {
    u32 cnt = *count; if (cnt > CAP) cnt = CAP;
    for (u32 i = blockIdx.x * 256 + threadIdx.x; i < cnt; i += 256u * 256u) {
        u32 e = list[i];
        int pixel = (int)(e >> 13), code = (int)(e & 8191u);
        const float* zp = z + (pixel >> 12) * BHW + (pixel & 4095);
        const float* ep = emb + code * C_DIM;
        float dot = 0.0f;
#pragma unroll
        for (int c = 0; c < C_DIM; ++c)
            dot = __builtin_fmaf(zp[c * HW], ep[c], dot);
        float dist = __fsub_rn(__fadd_rn(Sarr[pixel], Etab[code]),
                               __fmul_rn(2.0f, dot));
        u64 key = ((u64)__float_as_uint(dist) << 32) | (u32)code;  // dist > 0
        atomicMin(&best[pixel], key);
    }
}

// Gather z_q, write idx + z_q_st (NCHW), accumulate f64 loss partials.
__global__ __launch_bounds__(256) void k_final(const float* __restrict__ z,
                                               const float* __restrict__ emb,
                                               const u64* __restrict__ best,
                                               float* __restrict__ out,
                                               double* __restrict__ lpart) {
    const int n  = blockIdx.x * 256 + threadIdx.x;
    const int b  = n >> 12;
    const int hw = n & 4095;
    const u32 m  = (u32)(best[n] & 0xFFFFFFFFull);
    out[OUT_IDX_OFF + n] = (float)m;

    const float* zp = z + b * BHW + hw;
    const float* e  = emb + m * C_DIM;
    double lacc = 0.0;
#pragma unroll
    for (int c = 0; c < 64; ++c) {
        float zz   = zp[c * HW];
        float ec   = e[c];
        float diff = __fsub_rn(ec, zz);
        float outv = __fadd_rn(zz, diff);
        out[OUT_ZQ_OFF + b * BHW + c * HW + hw] = outv;
        lacc += (double)__fmul_rn(diff, diff);
    }
    __shared__ double sh[256];
    sh[threadIdx.x] = lacc;
    __syncthreads();
#pragma unroll
    for (int s = 128; s > 0; s >>= 1) {
        if (threadIdx.x < s) sh[threadIdx.x] += sh[threadIdx.x + s];
        __syncthreads();
    }
    if (threadIdx.x == 0) lpart[blockIdx.x] = sh[0];
}

__global__ void k_loss(const double* __restrict__ lpart, float* __restrict__ out) {
    if (threadIdx.x == 0 && blockIdx.x == 0) {
        double s = 0.0;
        for (int i = 0; i < 128; ++i) s += lpart[i];
        float m1 = (float)(s / (double)ZQ_N);
        out[0] = __fadd_rn(m1, __fmul_rn(0.25f, m1));
    }
}

extern "C" void kernel_launch(void* const* d_in, const int* in_sizes, int n_in,
                              void* d_out, int out_size, void* d_ws, size_t ws_size,
                              hipStream_t stream) {
    const float* z   = (const float*)d_in[0];
    const float* emb = (const float*)d_in[1];
    float* out = (float*)d_out;

    char* ws = (char*)d_ws;
    u64*    best  = (u64*)ws;
    float*  Etab  = (float*)(ws + WS_E_OFF);
    u32*    count = (u32*)(ws + WS_C_OFF);
    double* lpart = (double*)(ws + WS_L_OFF);

    float* SCR = out + 4;                       // 16B-aligned scratch in zq region
    u32*   zh   = (u32*)(SCR + OFF_ZH);
    u32*   eh   = (u32*)(SCR + OFF_EH);
    float* Sarr = SCR + OFF_S;
    float* Wp   = SCR + OFF_W;
    u32*   cmin = (u32*)(SCR + OFF_CMIN);
    u32*   list = (u32*)(SCR + OFF_LIST);

    k_init  <<<dim3(N_PIX / 256), dim3(256), 0, stream>>>(best, cmin, count, lpart);
    k_prep_z<<<dim3(N_PIX / 256), dim3(256), 0, stream>>>(z, zh, Sarr, Wp);
    k_prep_e<<<dim3(NE / 256),    dim3(256), 0, stream>>>(emb, eh, Etab);
    k_gemm<0><<<dim3(N_PIX / M_BLK, NE / N_SLICE), dim3(256), 0, stream>>>(
        (const uint4*)zh, (const bf16x8*)eh, Etab, Wp, cmin, count, list);
    k_gemm<1><<<dim3(N_PIX / M_BLK, NE / N_SLICE), dim3(256), 0, stream>>>(
        (const uint4*)zh, (const bf16x8*)eh, Etab, Wp, cmin, count, list);
    k_refine<<<dim3(256), dim3(256), 0, stream>>>(z, emb, Sarr, Etab, count, list, best);
    k_final <<<dim3(N_PIX / 256), dim3(256), 0, stream>>>(z, emb, best, out, lpart);
    k_loss  <<<dim3(1), dim3(64), 0, stream>>>(lpart, out);
}